// Round 3
// baseline (540.186 us; speedup 1.0000x reference)
//
#include <hip/hip_runtime.h>

typedef _Float16 f16x8 __attribute__((ext_vector_type(8)));
typedef _Float16 f16x4 __attribute__((ext_vector_type(4)));
typedef float    f32x4 __attribute__((ext_vector_type(4)));

#define MFMA(a,b,c) __builtin_amdgcn_mfma_f32_16x16x32_f16((a),(b),(c),0,0,0)

// ws layout (bytes): [0)      M~  f16 [128][128]  (scale * Wk^T Wq)
//                    [32768)  Wv' f16 [128][128]  (Wo @ Wv)
//                    [65536)  biases f32: t[128] = scale*Wk^T bq, b'[128] = Wo bv + bo
//                    [131072) Xg f16 [2048 g][128 rows=(d*4+p)][128 c]  (67.1 MB)
// Algebra: softmax over key-axis i is invariant to per-j offsets, so
//   S[i][j] = x_i^T (M x_j + t)  with M = scale*Wk^T Wq, t = scale*Wk^T bq
// (bk-only and constant terms drop). out = Wv' (X A) + b' + x.

// ---------------- prep: fold weights ----------------
__global__ __launch_bounds__(128) void prep_kernel(
    const float* __restrict__ Wk, const float* __restrict__ bk,
    const float* __restrict__ Wq, const float* __restrict__ bq,
    const float* __restrict__ Wv, const float* __restrict__ bv,
    const float* __restrict__ Wo, const float* __restrict__ bo,
    _Float16* __restrict__ wh, float* __restrict__ bf) {
  __shared__ float shK[128], shO[128];
  const int o = blockIdx.x;
  const int c = threadIdx.x;
  const float scale = 0.08838834764831844f;  // 1/sqrt(128)
  shK[c] = Wk[c*128 + o];      // Wk[m][o]  (column o)
  shO[c] = Wo[o*128 + c];      // Wo[o][m]
  __syncthreads();
  float aM = 0.f, aV = 0.f, tK = 0.f, bV = 0.f;
  for (int m = 0; m < 128; ++m) {
    aM += shK[m] * Wq[m*128 + c];   // M[o][c]
    aV += shO[m] * Wv[m*128 + c];   // Wv'[o][c]
    tK += shK[m] * bq[m];
    bV += shO[m] * bv[m];
  }
  wh[o*128 + c]         = (_Float16)(aM * scale);
  wh[16384 + o*128 + c] = (_Float16)aV;
  if (c == 0) { bf[o] = tK * scale; bf[128 + o] = bV + bo[o]; }
}

// ---------------- transpose v2: x fp32 [b,c,d,h,w] -> Xg f16 [g][d*4+p][c] ----------------
// grid = B*D*H = 4096 blocks, 256 thr. Lane packs 4 c's -> ds_write_b64
// (4 lanes per bank-pair = b64 minimum aliasing, effectively conflict-free).
__global__ __launch_bounds__(256) void transpose_kernel(
    const float* __restrict__ x, _Float16* __restrict__ Xg) {
  __shared__ _Float16 Lt[64 * 132];          // [w][c], stride 132 (264B, 8B-aligned rows)
  const int bid = blockIdx.x;
  const int h = bid & 63, d = (bid >> 6) & 31, b = bid >> 11;
  const int tid = threadIdx.x;
  const int wq = tid & 15, cr = tid >> 4;    // cr in [0,16)
  const size_t rbase = (size_t)b*16777216u + (size_t)d*4096 + h*64;
#pragma unroll
  for (int pass = 0; pass < 2; ++pass) {
    const int base_c = pass*64 + cr*4;
    f32x4 v[4];
#pragma unroll
    for (int r = 0; r < 4; ++r)
      v[r] = *(const f32x4*)(x + rbase + (size_t)(base_c + r)*131072 + wq*4);
#pragma unroll
    for (int p = 0; p < 4; ++p) {
      f16x4 t;
#pragma unroll
      for (int r = 0; r < 4; ++r) t[r] = (_Float16)v[r][p];
      *(f16x4*)(Lt + (wq*4 + p)*132 + base_c) = t;
    }
  }
  __syncthreads();
  // write: per w-row, 128 c contiguous (256B segments, line-aligned)
  const int gbase = b*1024 + h*16;
#pragma unroll
  for (int i = 0; i < 4; ++i) {
    const int idx = tid + i*256;             // 0..1023
    const int w = idx >> 4, ck = (idx & 15) * 8;
    const f16x8 v = *(const f16x8*)(Lt + w*132 + ck);
    *(f16x8*)(Xg + (size_t)(gbase + (w>>2))*16384 + (d*4 + (w&3))*128 + ck) = v;
  }
}

__device__ __forceinline__ f16x4 cvt4(f32x4 v, f32x4 b) {
  f16x4 r;
  r[0] = (_Float16)(v[0] + b[0]); r[1] = (_Float16)(v[1] + b[1]);
  r[2] = (_Float16)(v[2] + b[2]); r[3] = (_Float16)(v[3] + b[3]);
  return r;
}
__device__ __forceinline__ f16x4 cvt4z(f32x4 v) {
  f16x4 r;
  r[0] = (_Float16)v[0]; r[1] = (_Float16)v[1];
  r[2] = (_Float16)v[2]; r[3] = (_Float16)v[3];
  return r;
}

// XOR swizzle for Xt/Yt [128 rows][128 f16 cols], 256B rows, no padding.
__device__ __forceinline__ int xsw(int row, int col /*f16 units*/) {
  return ((row << 8) | (col << 1)) ^ (((row ^ (row >> 2)) & 7) << 4);
}

// ---------------- fused attention (persistent: 512 blocks x 4 iters) ----------------
// One pixel-group (4 consecutive w) per iteration. All 512 blocks co-resident
// (2/CU); out-stores of iter k drain under compute of iter k+1; next Xg tile
// prefetched to registers under P6. Residual folded into P6 via identity-MFMA.
__global__ __launch_bounds__(1024, 8) void attn_kernel(
    const _Float16* __restrict__ Xg, const _Float16* __restrict__ wh,
    const float* __restrict__ bfp, float* __restrict__ out) {
  __shared__ __align__(16) char lds[75776];
  char* XtB = lds;                      // [128 r=d*4+p][128 c] f16, swizzled
  char* YtB = lds + 32768;              // Y^T, later U^T, swizzled
  _Float16* At = (_Float16*)(lds + 65536);  // [p*32+j][40 i] f16

  const int tid  = threadIdx.x;
  const int lane = tid & 63;
  const int wv   = tid >> 6;
  const int quad = lane >> 4;
  const int l15  = lane & 15;
  const int bid  = blockIdx.x;
  const f32x4 zz = {0.f, 0.f, 0.f, 0.f};

  // persistent per-thread constants
  const int mi = wv & 7, ni = wv >> 3;          // P2 tiling
  const int oi = wv & 7, mg6 = wv >> 3;         // P6 tiling
  const int row1 = (tid + 0)    >> 4, ck1 = ((tid + 0)    & 15) * 8;   // P1 slot 0
  const int row2 = (tid + 1024) >> 4, ck2 = ((tid + 1024) & 15) * 8;   // P1 slot 1

  // M~ fragments + t bias (resident)
  f16x8 wm[4];
#pragma unroll
  for (int kk = 0; kk < 4; ++kk)
    wm[kk] = *(const f16x8*)(wh + (mi*16 + l15)*128 + kk*32 + quad*8);
  const f32x4 t4 = *(const f32x4*)(bfp + mi*16 + quad*4);
  const float bb = bfp[128 + oi*16 + l15];      // P6 output bias (resident)

  // identity B-fragment for residual MFMA: I block at k-cols ck0..ck0+31
  const int ck0 = (oi >> 1) * 32;
  union { f16x8 h; unsigned int u[4]; } wid;
  {
    const int t = (oi & 1)*16 + l15;            // diag position within 32-block
    const unsigned int ones = 0x3C00u << ((t & 1) * 16);
    const int hot = (quad == (t >> 3));
    const int j0 = (t >> 1) & 3;
    wid.u[0] = (hot && j0 == 0) ? ones : 0u;
    wid.u[1] = (hot && j0 == 1) ? ones : 0u;
    wid.u[2] = (hot && j0 == 2) ? ones : 0u;
    wid.u[3] = (hot && j0 == 3) ? ones : 0u;
  }

  // prefetch iter-0 Xg tile
  int orig = bid;
  int g = (orig & ~31) | ((orig & 7) << 2) | ((orig >> 3) & 3);
  f16x8 pf0 = *(const f16x8*)(Xg + (size_t)g*16384 + row1*128 + ck1);
  f16x8 pf1 = *(const f16x8*)(Xg + (size_t)g*16384 + row2*128 + ck2);

  for (int it = 0; it < 4; ++it) {
    const int b   = g >> 10;
    const int rem = g & 1023;
    const size_t pbase = (size_t)b * 16777216u + (size_t)((rem >> 4)*64 + (rem & 15)*4);

    // ---- P1: prefetched registers -> Xt (swizzled) ----
    *(f16x8*)(XtB + xsw(row1, ck1)) = pf0;
    *(f16x8*)(XtB + xsw(row2, ck2)) = pf1;
    __syncthreads();

    // ---- P2: Y = M~ X + t  -> Yt ----
    {
      f32x4 aY[4] = {zz, zz, zz, zz};
#pragma unroll
      for (int kk = 0; kk < 4; ++kk) {
        const int co = kk*32 + quad*8;
#pragma unroll
        for (int nt = 0; nt < 4; ++nt) {
          const f16x8 bfv = *(const f16x8*)(XtB + xsw(ni*64 + nt*16 + l15, co));
          aY[nt] = MFMA(wm[kk], bfv, aY[nt]);
        }
      }
#pragma unroll
      for (int nt = 0; nt < 4; ++nt)
        *(f16x4*)(YtB + xsw(ni*64 + nt*16 + l15, mi*16 + quad*4)) = cvt4(aY[nt], t4);
    }
    __syncthreads();

    // ---- P3: S = X^T Y per pixel (waves 0-3), wave-local softmax -> At ----
    if (wv < 4) {
      const int p = wv;
      f32x4 aS[2][2] = {{zz, zz}, {zz, zz}};
#pragma unroll
      for (int kk = 0; kk < 4; ++kk) {
        const int co = kk*32 + quad*8;
        f16x8 ak[2], by[2];
#pragma unroll
        for (int t = 0; t < 2; ++t) {
          ak[t] = *(const f16x8*)(XtB + xsw((t*16 + l15)*4 + p, co));
          by[t] = *(const f16x8*)(YtB + xsw((t*16 + l15)*4 + p, co));
        }
#pragma unroll
        for (int ti = 0; ti < 2; ++ti)
#pragma unroll
          for (int tj = 0; tj < 2; ++tj)
            aS[ti][tj] = MFMA(ak[ti], by[tj], aS[ti][tj]);
      }
#pragma unroll
      for (int tj = 0; tj < 2; ++tj) {
        float mx = aS[0][tj][0];
#pragma unroll
        for (int r = 1; r < 4; ++r) mx = fmaxf(mx, aS[0][tj][r]);
#pragma unroll
        for (int r = 0; r < 4; ++r) mx = fmaxf(mx, aS[1][tj][r]);
        mx = fmaxf(mx, __shfl_xor(mx, 16));
        mx = fmaxf(mx, __shfl_xor(mx, 32));
        float e[2][4];
        float den = 0.f;
#pragma unroll
        for (int ti = 0; ti < 2; ++ti)
#pragma unroll
          for (int r = 0; r < 4; ++r) { e[ti][r] = __expf(aS[ti][tj][r] - mx); den += e[ti][r]; }
        den += __shfl_xor(den, 16);
        den += __shfl_xor(den, 32);
        const float rr = 1.0f / den;
#pragma unroll
        for (int ti = 0; ti < 2; ++ti) {
          f16x4 av;
#pragma unroll
          for (int r = 0; r < 4; ++r) av[r] = (_Float16)(e[ti][r] * rr);
          *(f16x4*)(At + (p*32 + tj*16 + l15)*40 + ti*16 + quad*4) = av;
        }
      }
    }
    __syncthreads();

    // ---- P5: U = X A per pixel -> Yt (U^T rows j*4+p); wp loaded per iter ----
    {
      f16x8 wp_[4];
#pragma unroll
      for (int kk = 0; kk < 4; ++kk)
        wp_[kk] = *(const f16x8*)(wh + 16384 + (mi*16 + l15)*128 + kk*32 + quad*8);
      (void)wp_[0];  // consumed in P6 via recompute below? no — keep P5-local U only
      const int p = wv & 3, mg = wv >> 2;
      f16x8 bA[2];
#pragma unroll
      for (int tj = 0; tj < 2; ++tj)
        bA[tj] = *(const f16x8*)(At + (p*32 + tj*16 + l15)*40 + quad*8);
#pragma unroll
      for (int t2 = 0; t2 < 2; ++t2) {
        const int ms = mg*2 + t2;
        f16x8 ax;
#pragma unroll
        for (int jj = 0; jj < 8; ++jj)
          ax[jj] = *(const _Float16*)(XtB + xsw((quad*8 + jj)*4 + p, ms*16 + l15));
#pragma unroll
        for (int tj = 0; tj < 2; ++tj) {
          const f32x4 aU = MFMA(ax, bA[tj], zz);
          *(f16x4*)(YtB + xsw((tj*16 + l15)*4 + p, ms*16 + quad*4)) = cvt4z(aU);
        }
      }
    }
    __syncthreads();

    // ---- prefetch next iteration's Xg tile (hides HBM/L3 latency under P6) ----
    if (it < 3) {
      const int orign = orig + 512;
      const int gn = (orign & ~31) | ((orign & 7) << 2) | ((orign >> 3) & 3);
      pf0 = *(const f16x8*)(Xg + (size_t)gn*16384 + row1*128 + ck1);
      pf1 = *(const f16x8*)(Xg + (size_t)gn*16384 + row2*128 + ck2);
      orig = orign;
      g = gn;
    }

    // ---- P6: out^T = U^T Wv'^T + b' + X^T·I : direct f32x4 stores ----
    {
      f16x8 wp[4];
#pragma unroll
      for (int kk = 0; kk < 4; ++kk)
        wp[kk] = *(const f16x8*)(wh + 16384 + (oi*16 + l15)*128 + kk*32 + quad*8);
      f32x4 acc[4] = {zz, zz, zz, zz};
#pragma unroll
      for (int kk = 0; kk < 4; ++kk) {
        const int co = kk*32 + quad*8;
#pragma unroll
        for (int mt = 0; mt < 4; ++mt) {
          const f16x8 av = *(const f16x8*)(YtB + xsw((mg6*4 + mt)*16 + l15, co));
          acc[mt] = MFMA(av, wp[kk], acc[mt]);
        }
      }
      // residual: acc += X^T · I  (A-op = Xt rows, B-op = sparse identity frag)
#pragma unroll
      for (int mt = 0; mt < 4; ++mt) {
        const f16x8 axr = *(const f16x8*)(XtB + xsw((mg6*4 + mt)*16 + l15, ck0 + quad*8));
        acc[mt] = MFMA(axr, wid.h, acc[mt]);
      }
      const int o = oi*16 + l15;
      float* outp = out + pbase + (size_t)o*131072;
#pragma unroll
      for (int mt = 0; mt < 4; ++mt) {
        const int colb = (mg6*4 + mt)*16 + quad*4;   // = d*4 (reg index = w offset)
        const int d = colb >> 2;
        f32x4 v;
#pragma unroll
        for (int r = 0; r < 4; ++r) v[r] = acc[mt][r] + bb;
        *(f32x4*)(outp + (size_t)d*4096) = v;
      }
    }
    __syncthreads();   // all P6 LDS reads done before next iter's Xt/Yt writes
  }
}

extern "C" void kernel_launch(void* const* d_in, const int* in_sizes, int n_in,
                              void* d_out, int out_size, void* d_ws, size_t ws_size,
                              hipStream_t stream) {
  const float* x  = (const float*)d_in[0];
  const float* Wk = (const float*)d_in[1];
  const float* bk = (const float*)d_in[2];
  const float* Wq = (const float*)d_in[3];
  const float* bq = (const float*)d_in[4];
  const float* Wv = (const float*)d_in[5];
  const float* bv = (const float*)d_in[6];
  const float* Wo = (const float*)d_in[7];
  const float* bo = (const float*)d_in[8];
  float* out = (float*)d_out;
  _Float16* wh = (_Float16*)d_ws;
  float* bf = (float*)((char*)d_ws + 65536);
  _Float16* Xg = (_Float16*)((char*)d_ws + 131072);  // needs 67.1 MB of ws

  prep_kernel<<<dim3(128), dim3(128), 0, stream>>>(Wk, bk, Wq, bq, Wv, bv, Wo, bo, wh, bf);
  transpose_kernel<<<dim3(4096), dim3(256), 0, stream>>>(x, Xg);
  attn_kernel<<<dim3(512), dim3(1024), 0, stream>>>(Xg, wh, bf, out);
}

// Round 4
// 364.649 us; speedup vs baseline: 1.4814x; 1.4814x over previous
//
#include <hip/hip_runtime.h>

typedef _Float16 f16x8 __attribute__((ext_vector_type(8)));
typedef _Float16 f16x4 __attribute__((ext_vector_type(4)));
typedef float    f32x4 __attribute__((ext_vector_type(4)));

#define MFMA(a,b,c) __builtin_amdgcn_mfma_f32_16x16x32_f16((a),(b),(c),0,0,0)

// ws layout (bytes): [0)      M~  f16 [128][128]  (scale * Wk^T Wq)
//                    [32768)  Wv' f16 [128][128]  (Wo @ Wv)
//                    [65536)  biases f32: t[128] = scale*Wk^T bq, b'[128] = Wo bv + bo
//                    [131072) Xg f16 [2048 g][128 rows=(d*4+p)][128 c]  (67.1 MB)
// Algebra: softmax over key-axis i is invariant to per-j offsets, so
//   S[i][j] = x_i^T (M x_j + t)  with M = scale*Wk^T Wq, t = scale*Wk^T bq
// (bk-only and constant terms drop). out = Wv' (X A) + b' + x.

// ---------------- prep: fold weights ----------------
__global__ __launch_bounds__(128) void prep_kernel(
    const float* __restrict__ Wk, const float* __restrict__ bk,
    const float* __restrict__ Wq, const float* __restrict__ bq,
    const float* __restrict__ Wv, const float* __restrict__ bv,
    const float* __restrict__ Wo, const float* __restrict__ bo,
    _Float16* __restrict__ wh, float* __restrict__ bf) {
  __shared__ float shK[128], shO[128];
  const int o = blockIdx.x;
  const int c = threadIdx.x;
  const float scale = 0.08838834764831844f;  // 1/sqrt(128)
  shK[c] = Wk[c*128 + o];      // Wk[m][o]  (column o)
  shO[c] = Wo[o*128 + c];      // Wo[o][m]
  __syncthreads();
  float aM = 0.f, aV = 0.f, tK = 0.f, bV = 0.f;
  for (int m = 0; m < 128; ++m) {
    aM += shK[m] * Wq[m*128 + c];   // M[o][c]
    aV += shO[m] * Wv[m*128 + c];   // Wv'[o][c]
    tK += shK[m] * bq[m];
    bV += shO[m] * bv[m];
  }
  wh[o*128 + c]         = (_Float16)(aM * scale);
  wh[16384 + o*128 + c] = (_Float16)aV;
  if (c == 0) { bf[o] = tK * scale; bf[128 + o] = bV + bo[o]; }
}

// ---------------- transpose v2: x fp32 [b,c,d,h,w] -> Xg f16 [g][d*4+p][c] ----------------
// grid = B*D*H = 4096 blocks, 256 thr. Lane packs 4 c's -> ds_write_b64
// (4 lanes per bank-pair = b64 minimum aliasing, effectively conflict-free).
// Measured ~32us (vs ~72us for the scalar-ds_write v1).
__global__ __launch_bounds__(256) void transpose_kernel(
    const float* __restrict__ x, _Float16* __restrict__ Xg) {
  __shared__ _Float16 Lt[64 * 132];          // [w][c], stride 132 (264B, 8B-aligned rows)
  const int bid = blockIdx.x;
  const int h = bid & 63, d = (bid >> 6) & 31, b = bid >> 11;
  const int tid = threadIdx.x;
  const int wq = tid & 15, cr = tid >> 4;    // cr in [0,16)
  const size_t rbase = (size_t)b*16777216u + (size_t)d*4096 + h*64;
#pragma unroll
  for (int pass = 0; pass < 2; ++pass) {
    const int base_c = pass*64 + cr*4;
    f32x4 v[4];
#pragma unroll
    for (int r = 0; r < 4; ++r)
      v[r] = *(const f32x4*)(x + rbase + (size_t)(base_c + r)*131072 + wq*4);
#pragma unroll
    for (int p = 0; p < 4; ++p) {
      f16x4 t;
#pragma unroll
      for (int r = 0; r < 4; ++r) t[r] = (_Float16)v[r][p];
      *(f16x4*)(Lt + (wq*4 + p)*132 + base_c) = t;
    }
  }
  __syncthreads();
  // write: per w-row, 128 c contiguous (256B segments, line-aligned)
  const int gbase = b*1024 + h*16;
#pragma unroll
  for (int i = 0; i < 4; ++i) {
    const int idx = tid + i*256;             // 0..1023
    const int w = idx >> 4, ck = (idx & 15) * 8;
    const f16x8 v = *(const f16x8*)(Lt + w*132 + ck);
    *(f16x8*)(Xg + (size_t)(gbase + (w>>2))*16384 + (d*4 + (w&3))*128 + ck) = v;
  }
}

__device__ __forceinline__ f16x4 cvt4(f32x4 v, f32x4 b) {
  f16x4 r;
  r[0] = (_Float16)(v[0] + b[0]); r[1] = (_Float16)(v[1] + b[1]);
  r[2] = (_Float16)(v[2] + b[2]); r[3] = (_Float16)(v[3] + b[3]);
  return r;
}
__device__ __forceinline__ f16x4 cvt4z(f32x4 v) {
  f16x4 r;
  r[0] = (_Float16)v[0]; r[1] = (_Float16)v[1];
  r[2] = (_Float16)v[2]; r[3] = (_Float16)v[3];
  return r;
}

// XOR swizzle for Xt/Yt [128 rows][128 f16 cols], 256B rows, no padding.
// byte addr, 16B-chunk bits XORed with (row ^ row>>2)&7 so that stride-1-row,
// stride-4-row and column accesses all spread across banks.
__device__ __forceinline__ int xsw(int row, int col /*f16 units*/) {
  return ((row << 8) | (col << 1)) ^ (((row ^ (row >> 2)) & 7) << 4);
}

// ---------------- fused attention ----------------
// grid = 2048 blocks x 1024 thr; one pixel-group (4 consecutive w) per block.
// NOT persistent: fresh phase-aligned blocks are what keep the 4 siblings
// sharing each 64B out-line concurrent on their XCD so L2 merges the 16B
// granules (round-3 persistence desynced them: WRITE 250->455MB, FETCH +290MB).
// Xt rows ordered d*4+p so the output GEMM (computed transposed) gives each
// lane 4 accumulator values = out[o][d][w0..w0+3] -> direct f32x4 stores.
// LDS 75.8KB -> 2 blocks/CU; VGPR capped at 64 via launch_bounds(1024,8).
__global__ __launch_bounds__(1024, 8) void attn_kernel(
    const _Float16* __restrict__ Xg, const _Float16* __restrict__ wh,
    const float* __restrict__ bfp, float* __restrict__ out) {
  __shared__ __align__(16) char lds[75776];
  char* XtB = lds;                      // [128 r=d*4+p][128 c] f16, swizzled
  char* YtB = lds + 32768;              // Y^T, later U^T, swizzled
  _Float16* At = (_Float16*)(lds + 65536);  // [p*32+j][40 i] f16

  const int tid  = threadIdx.x;
  const int lane = tid & 63;
  const int wv   = tid >> 6;
  const int quad = lane >> 4;
  const int l15  = lane & 15;

  const int bid = blockIdx.x;
  const int g = (bid & ~31) | ((bid & 7) << 2) | ((bid >> 3) & 3);
  const int b   = g >> 10;
  const int rem = g & 1023;
  const int h   = rem >> 4;
  const int wg  = rem & 15;
  const size_t pbase = (size_t)b * 16777216u + (size_t)(h*64 + wg*4);
  const f32x4 zz = {0.f, 0.f, 0.f, 0.f};

  // ---- prefetch M~ fragments + bias (in flight during P1) ----
  const int mi = wv & 7, ni = wv >> 3;
  f16x8 wm[4];
#pragma unroll
  for (int kk = 0; kk < 4; ++kk)
    wm[kk] = *(const f16x8*)(wh + (mi*16 + l15)*128 + kk*32 + quad*8);
  const f32x4 t4 = *(const f32x4*)(bfp + mi*16 + quad*4);

  // ---- P1: coalesced load of this group's 32KB f16 chunk -> Xt (swizzled) ----
  {
    const _Float16* src = Xg + (size_t)g * 16384;
#pragma unroll
    for (int i = 0; i < 2; ++i) {
      const int idx = tid + i*1024;          // 0..2047
      const int row = idx >> 4, ck = (idx & 15) * 8;
      const f16x8 v = *(const f16x8*)(src + row*128 + ck);
      *(f16x8*)(XtB + xsw(row, ck)) = v;
    }
  }
  __syncthreads();

  // ---- P2: Y = M~ X + t  -> Yt (rows = voxel col, cols = c1) ----
  {
    f32x4 aY[4] = {zz, zz, zz, zz};
#pragma unroll
    for (int kk = 0; kk < 4; ++kk) {
      const int co = kk*32 + quad*8;
#pragma unroll
      for (int nt = 0; nt < 4; ++nt) {
        const f16x8 bfv = *(const f16x8*)(XtB + xsw(ni*64 + nt*16 + l15, co));
        aY[nt] = MFMA(wm[kk], bfv, aY[nt]);
      }
    }
#pragma unroll
    for (int nt = 0; nt < 4; ++nt)
      *(f16x4*)(YtB + xsw(ni*64 + nt*16 + l15, mi*16 + quad*4)) = cvt4(aY[nt], t4);
  }
  __syncthreads();

  // ---- P3: S = X^T Y per pixel (waves 0-3), wave-local softmax over i -> At ----
  if (wv < 4) {
    const int p = wv;
    f32x4 aS[2][2] = {{zz, zz}, {zz, zz}};
#pragma unroll
    for (int kk = 0; kk < 4; ++kk) {
      const int co = kk*32 + quad*8;
      f16x8 ak[2], by[2];
#pragma unroll
      for (int t = 0; t < 2; ++t) {
        ak[t] = *(const f16x8*)(XtB + xsw((t*16 + l15)*4 + p, co));
        by[t] = *(const f16x8*)(YtB + xsw((t*16 + l15)*4 + p, co));
      }
#pragma unroll
      for (int ti = 0; ti < 2; ++ti)
#pragma unroll
        for (int tj = 0; tj < 2; ++tj)
          aS[ti][tj] = MFMA(ak[ti], by[tj], aS[ti][tj]);
    }
    // softmax over i (32) for j = tj*16+l15: 8 local + butterfly over quads
#pragma unroll
    for (int tj = 0; tj < 2; ++tj) {
      float mx = aS[0][tj][0];
#pragma unroll
      for (int r = 1; r < 4; ++r) mx = fmaxf(mx, aS[0][tj][r]);
#pragma unroll
      for (int r = 0; r < 4; ++r) mx = fmaxf(mx, aS[1][tj][r]);
      mx = fmaxf(mx, __shfl_xor(mx, 16));
      mx = fmaxf(mx, __shfl_xor(mx, 32));
      float e[2][4];
      float den = 0.f;
#pragma unroll
      for (int ti = 0; ti < 2; ++ti)
#pragma unroll
        for (int r = 0; r < 4; ++r) { e[ti][r] = __expf(aS[ti][tj][r] - mx); den += e[ti][r]; }
      den += __shfl_xor(den, 16);
      den += __shfl_xor(den, 32);
      const float rr = 1.0f / den;
#pragma unroll
      for (int ti = 0; ti < 2; ++ti) {
        f16x4 av;
#pragma unroll
        for (int r = 0; r < 4; ++r) av[r] = (_Float16)(e[ti][r] * rr);
        *(f16x4*)(At + (p*32 + tj*16 + l15)*40 + ti*16 + quad*4) = av;
      }
    }
  }
  __syncthreads();

  // ---- P5: U = X A per pixel -> Yt (U^T rows = j*4+p, cols = c); prefetch Wv' ----
  f16x8 wp[4];
  {
#pragma unroll
    for (int kk = 0; kk < 4; ++kk)
      wp[kk] = *(const f16x8*)(wh + 16384 + ((wv & 7)*16 + l15)*128 + kk*32 + quad*8);
    const int p = wv & 3, mg = wv >> 2;
    f16x8 bA[2];
#pragma unroll
    for (int tj = 0; tj < 2; ++tj)
      bA[tj] = *(const f16x8*)(At + (p*32 + tj*16 + l15)*40 + quad*8);
#pragma unroll
    for (int t2 = 0; t2 < 2; ++t2) {
      const int ms = mg*2 + t2;
      f16x8 ax;
#pragma unroll
      for (int jj = 0; jj < 8; ++jj)
        ax[jj] = *(const _Float16*)(XtB + xsw((quad*8 + jj)*4 + p, ms*16 + l15));
#pragma unroll
      for (int tj = 0; tj < 2; ++tj) {
        const f32x4 aU = MFMA(ax, bA[tj], zz);
        *(f16x4*)(YtB + xsw((tj*16 + l15)*4 + p, ms*16 + quad*4)) = cvt4z(aU);
      }
    }
  }
  __syncthreads();

  // ---- P6: out^T = U^T Wv'^T + b' + x : direct f32x4 stores ----
  {
    const int oi = wv & 7, mg6 = wv >> 3;
    f32x4 acc[4] = {zz, zz, zz, zz};
#pragma unroll
    for (int kk = 0; kk < 4; ++kk) {
      const int co = kk*32 + quad*8;
#pragma unroll
      for (int mt = 0; mt < 4; ++mt) {
        const f16x8 av = *(const f16x8*)(YtB + xsw((mg6*4 + mt)*16 + l15, co));
        acc[mt] = MFMA(av, wp[kk], acc[mt]);
      }
    }
    const int o = oi*16 + l15;
    const float bb = bfp[128 + o];
    float* outp = out + pbase + (size_t)o*131072;
#pragma unroll
    for (int mt = 0; mt < 4; ++mt) {
      const int colb = (mg6*4 + mt)*16 + quad*4;   // = d*4 (p = reg index)
      const int d = colb >> 2;
      f32x4 v;
#pragma unroll
      for (int r = 0; r < 4; ++r)
        v[r] = acc[mt][r] + bb +
               (float)*(const _Float16*)(XtB + xsw(colb + r, o));
      *(f32x4*)(outp + (size_t)d*4096) = v;
    }
  }
}

extern "C" void kernel_launch(void* const* d_in, const int* in_sizes, int n_in,
                              void* d_out, int out_size, void* d_ws, size_t ws_size,
                              hipStream_t stream) {
  const float* x  = (const float*)d_in[0];
  const float* Wk = (const float*)d_in[1];
  const float* bk = (const float*)d_in[2];
  const float* Wq = (const float*)d_in[3];
  const float* bq = (const float*)d_in[4];
  const float* Wv = (const float*)d_in[5];
  const float* bv = (const float*)d_in[6];
  const float* Wo = (const float*)d_in[7];
  const float* bo = (const float*)d_in[8];
  float* out = (float*)d_out;
  _Float16* wh = (_Float16*)d_ws;
  float* bf = (float*)((char*)d_ws + 65536);
  _Float16* Xg = (_Float16*)((char*)d_ws + 131072);  // needs 67.1 MB of ws

  prep_kernel<<<dim3(128), dim3(128), 0, stream>>>(Wk, bk, Wq, bq, Wv, bv, Wo, bo, wh, bf);
  transpose_kernel<<<dim3(4096), dim3(256), 0, stream>>>(x, Xg);
  attn_kernel<<<dim3(2048), dim3(1024), 0, stream>>>(Xg, wh, bf, out);
}

// Round 5
// 343.579 us; speedup vs baseline: 1.5722x; 1.0613x over previous
//
#include <hip/hip_runtime.h>

typedef _Float16 f16x8 __attribute__((ext_vector_type(8)));
typedef _Float16 f16x4 __attribute__((ext_vector_type(4)));
typedef float    f32x4 __attribute__((ext_vector_type(4)));

#define MFMA(a,b,c) __builtin_amdgcn_mfma_f32_16x16x32_f16((a),(b),(c),0,0,0)

// ws layout (bytes): [0)      M~  f16 [128][128]  (scale * Wk^T Wq)
//                    [32768)  Wv' f16 [128][128]  (Wo @ Wv)
//                    [65536)  biases f32: t[128] = scale*Wk^T bq, b'[128] = Wo bv + bo
//                    [131072) Xg f16 [1024 g][256 rows=(d*8+p)][128 c]  (67.1 MB)
// Algebra: softmax over key-axis i is invariant to per-j offsets, so
//   S[i][j] = x_i^T (M x_j + t)  with M = scale*Wk^T Wq, t = scale*Wk^T bq
// (bk-only and constant terms drop). out = Wv' (X A) + b' + x.

// ---------------- prep: fold weights ----------------
__global__ __launch_bounds__(128) void prep_kernel(
    const float* __restrict__ Wk, const float* __restrict__ bk,
    const float* __restrict__ Wq, const float* __restrict__ bq,
    const float* __restrict__ Wv, const float* __restrict__ bv,
    const float* __restrict__ Wo, const float* __restrict__ bo,
    _Float16* __restrict__ wh, float* __restrict__ bf) {
  __shared__ float shK[128], shO[128];
  const int o = blockIdx.x;
  const int c = threadIdx.x;
  const float scale = 0.08838834764831844f;  // 1/sqrt(128)
  shK[c] = Wk[c*128 + o];      // Wk[m][o]  (column o)
  shO[c] = Wo[o*128 + c];      // Wo[o][m]
  __syncthreads();
  float aM = 0.f, aV = 0.f, tK = 0.f, bV = 0.f;
  for (int m = 0; m < 128; ++m) {
    aM += shK[m] * Wq[m*128 + c];   // M[o][c]
    aV += shO[m] * Wv[m*128 + c];   // Wv'[o][c]
    tK += shK[m] * bq[m];
    bV += shO[m] * bv[m];
  }
  wh[o*128 + c]         = (_Float16)(aM * scale);
  wh[16384 + o*128 + c] = (_Float16)aV;
  if (c == 0) { bf[o] = tK * scale; bf[128 + o] = bV + bo[o]; }
}

// ---------------- transpose v2: x fp32 [b,c,d,h,w] -> Xg f16 [g][d*8+p][c] ----------------
// grid = B*D*H = 4096 blocks, 256 thr. Lane packs 4 c's -> ds_write_b64.
__global__ __launch_bounds__(256) void transpose_kernel(
    const float* __restrict__ x, _Float16* __restrict__ Xg) {
  __shared__ _Float16 Lt[64 * 132];          // [w][c], stride 132 (264B, 8B-aligned rows)
  const int bid = blockIdx.x;
  const int h = bid & 63, d = (bid >> 6) & 31, b = bid >> 11;
  const int tid = threadIdx.x;
  const int wq = tid & 15, cr = tid >> 4;    // cr in [0,16)
  const size_t rbase = (size_t)b*16777216u + (size_t)d*4096 + h*64;
#pragma unroll
  for (int pass = 0; pass < 2; ++pass) {
    const int base_c = pass*64 + cr*4;
    f32x4 v[4];
#pragma unroll
    for (int r = 0; r < 4; ++r)
      v[r] = *(const f32x4*)(x + rbase + (size_t)(base_c + r)*131072 + wq*4);
#pragma unroll
    for (int p = 0; p < 4; ++p) {
      f16x4 t;
#pragma unroll
      for (int r = 0; r < 4; ++r) t[r] = (_Float16)v[r][p];
      *(f16x4*)(Lt + (wq*4 + p)*132 + base_c) = t;
    }
  }
  __syncthreads();
  // write: per w-row, 128 c contiguous (256B segments, line-aligned)
  const int gbase = (b*64 + h)*8;            // 8 groups per (b,h)
#pragma unroll
  for (int i = 0; i < 4; ++i) {
    const int idx = tid + i*256;             // 0..1023
    const int w = idx >> 4, ck = (idx & 15) * 8;
    const f16x8 v = *(const f16x8*)(Lt + w*132 + ck);
    *(f16x8*)(Xg + (size_t)(gbase + (w>>3))*32768 + (d*8 + (w&7))*128 + ck) = v;
  }
}

__device__ __forceinline__ f16x4 cvt4(f32x4 v, f32x4 b) {
  f16x4 r;
  r[0] = (_Float16)(v[0] + b[0]); r[1] = (_Float16)(v[1] + b[1]);
  r[2] = (_Float16)(v[2] + b[2]); r[3] = (_Float16)(v[3] + b[3]);
  return r;
}
__device__ __forceinline__ f16x4 cvt4z(f32x4 v) {
  f16x4 r;
  r[0] = (_Float16)v[0]; r[1] = (_Float16)v[1];
  r[2] = (_Float16)v[2]; r[3] = (_Float16)v[3];
  return r;
}

// XOR swizzle for Xt/Yt [256 rows][128 f16 cols], 256B rows, no padding.
// XOR folds row, row>>3 (stride-8-row accesses) and row>>5 (stride-64) so
// all phase patterns land >=8 distinct 16B chunks per 16 lanes.
__device__ __forceinline__ int xsw(int row, int col /*f16 units*/) {
  return ((row << 8) | (col << 1)) ^ (((row ^ (row >> 3) ^ (row >> 5)) & 7) << 4);
}

// ---------------- fused attention (N=8: one 8-w pixel-group pair per block) ----------------
// grid = 1024 blocks x 1024 thr; 8 consecutive w per block -> each wave's quad
// pair stores 32B per 64B out-line (native HBM sector, no cross-block merge
// needed; round-4 showed lone 16B granules cost exactly 2x WRITE).
// LDS 148KB -> 1 block/CU: all CUs lockstep -> sibling blocks (other line
// half) store concurrently anyway (round-0 evidence: 1 blk/CU merged fully).
__global__ __launch_bounds__(1024, 4) void attn_kernel(
    const _Float16* __restrict__ Xg, const _Float16* __restrict__ wh,
    const float* __restrict__ bfp, float* __restrict__ out) {
  __shared__ __align__(16) char lds[151552];
  char* XtB = lds;                      // [256 r=d*8+p][128 c] f16, swizzled (64KB)
  char* YtB = lds + 65536;              // Y^T, later U^T, swizzled (64KB)
  _Float16* At = (_Float16*)(lds + 131072);  // [p*32+j][40 i] f16 (20KB)

  const int tid  = threadIdx.x;
  const int lane = tid & 63;
  const int wv   = tid >> 6;            // 0..15
  const int quad = lane >> 4;
  const int l15  = lane & 15;

  const int bid = blockIdx.x;
  // sibling pairing: g and g^1 (the two halves of each 64B out-line) are
  // bids 8 apart -> same XCD (bid%8 equal), dispatched adjacently.
  const int g = (bid & ~15) | ((bid & 7) << 1) | ((bid >> 3) & 1);
  const int b   = g >> 9;
  const int rem = g & 511;
  const int h   = rem >> 3;
  const int wg  = rem & 7;
  const size_t pbase = (size_t)b * 16777216u + (size_t)(h*64 + wg*8);
  const f32x4 zz = {0.f, 0.f, 0.f, 0.f};

  // ---- prefetch M~ fragments + bias (in flight during P1) ----
  const int mi = wv & 7, ni = wv >> 3;
  f16x8 wm[4];
#pragma unroll
  for (int kk = 0; kk < 4; ++kk)
    wm[kk] = *(const f16x8*)(wh + (mi*16 + l15)*128 + kk*32 + quad*8);
  const f32x4 t4 = *(const f32x4*)(bfp + mi*16 + quad*4);

  // ---- P1: coalesced load of this group's 64KB f16 chunk -> Xt (swizzled) ----
  {
    const _Float16* src = Xg + (size_t)g * 32768;
#pragma unroll
    for (int i = 0; i < 4; ++i) {
      const int idx = tid + i*1024;          // 0..4095
      const int row = idx >> 4, ck = (idx & 15) * 8;
      const f16x8 v = *(const f16x8*)(src + row*128 + ck);
      *(f16x8*)(XtB + xsw(row, ck)) = v;
    }
  }
  __syncthreads();

  // ---- P2: Y = M~ X + t  -> Yt (rows = voxel d*8+p, cols = c1) ----
  {
    f32x4 aY[8] = {zz, zz, zz, zz, zz, zz, zz, zz};
#pragma unroll
    for (int kk = 0; kk < 4; ++kk) {
      const int co = kk*32 + quad*8;
#pragma unroll
      for (int nt = 0; nt < 8; ++nt) {
        const f16x8 bfv = *(const f16x8*)(XtB + xsw(ni*128 + nt*16 + l15, co));
        aY[nt] = MFMA(wm[kk], bfv, aY[nt]);
      }
    }
#pragma unroll
    for (int nt = 0; nt < 8; ++nt)
      *(f16x4*)(YtB + xsw(ni*128 + nt*16 + l15, mi*16 + quad*4)) = cvt4(aY[nt], t4);
  }
  __syncthreads();

  // ---- P3: S = X^T Y per pixel; wave = (pixel p, j-half tj); softmax -> At ----
  {
    const int p = wv & 7, tj = wv >> 3;
    f32x4 aS[2] = {zz, zz};
#pragma unroll
    for (int kk = 0; kk < 4; ++kk) {
      const int co = kk*32 + quad*8;
      const f16x8 by = *(const f16x8*)(YtB + xsw((tj*16 + l15)*8 + p, co));
#pragma unroll
      for (int ti = 0; ti < 2; ++ti) {
        const f16x8 ak = *(const f16x8*)(XtB + xsw((ti*16 + l15)*8 + p, co));
        aS[ti] = MFMA(ak, by, aS[ti]);
      }
    }
    // lane holds S[i = ti*16+quad*4+r][j = tj*16+l15]; reduce over i
    float mx = aS[0][0];
#pragma unroll
    for (int r = 1; r < 4; ++r) mx = fmaxf(mx, aS[0][r]);
#pragma unroll
    for (int r = 0; r < 4; ++r) mx = fmaxf(mx, aS[1][r]);
    mx = fmaxf(mx, __shfl_xor(mx, 16));
    mx = fmaxf(mx, __shfl_xor(mx, 32));
    float e[2][4];
    float den = 0.f;
#pragma unroll
    for (int ti = 0; ti < 2; ++ti)
#pragma unroll
      for (int r = 0; r < 4; ++r) { e[ti][r] = __expf(aS[ti][r] - mx); den += e[ti][r]; }
    den += __shfl_xor(den, 16);
    den += __shfl_xor(den, 32);
    const float rr = 1.0f / den;
#pragma unroll
    for (int ti = 0; ti < 2; ++ti) {
      f16x4 av;
#pragma unroll
      for (int r = 0; r < 4; ++r) av[r] = (_Float16)(e[ti][r] * rr);
      *(f16x4*)(At + (p*32 + tj*16 + l15)*40 + ti*16 + quad*4) = av;
    }
  }
  __syncthreads();

  // ---- P5: U = X A per pixel -> Yt (U^T rows = j*8+p); prefetch Wv' ----
  f16x8 wp[4];
  {
#pragma unroll
    for (int kk = 0; kk < 4; ++kk)
      wp[kk] = *(const f16x8*)(wh + 16384 + (mi*16 + l15)*128 + kk*32 + quad*8);
    const int p = wv & 7, mg = wv >> 3;
    f16x8 bA[2];
#pragma unroll
    for (int tj = 0; tj < 2; ++tj)
      bA[tj] = *(const f16x8*)(At + (p*32 + tj*16 + l15)*40 + quad*8);
#pragma unroll
    for (int t2 = 0; t2 < 4; ++t2) {
      const int ms = mg*4 + t2;
      f16x8 ax;
#pragma unroll
      for (int jj = 0; jj < 8; ++jj)
        ax[jj] = *(const _Float16*)(XtB + xsw((quad*8 + jj)*8 + p, ms*16 + l15));
#pragma unroll
      for (int tj = 0; tj < 2; ++tj) {
        const f32x4 aU = MFMA(ax, bA[tj], zz);
        *(f16x4*)(YtB + xsw((tj*16 + l15)*8 + p, ms*16 + quad*4)) = cvt4z(aU);
      }
    }
  }
  __syncthreads();

  // ---- P6: out^T = U^T Wv'^T + b' + x : 32B/line stores (quad pairs) ----
  {
    const int oi = wv & 7, mg6 = wv >> 3;
    f32x4 acc[8] = {zz, zz, zz, zz, zz, zz, zz, zz};
#pragma unroll
    for (int kk = 0; kk < 4; ++kk) {
      const int co = kk*32 + quad*8;
#pragma unroll
      for (int mt = 0; mt < 8; ++mt) {
        const f16x8 av = *(const f16x8*)(YtB + xsw((mg6*8 + mt)*16 + l15, co));
        acc[mt] = MFMA(av, wp[kk], acc[mt]);
      }
    }
    const int o = oi*16 + l15;
    const float bb = bfp[128 + o];
    float* outp = out + pbase + (size_t)o*131072;
#pragma unroll
    for (int mt = 0; mt < 8; ++mt) {
      const int vox0 = (mg6*8 + mt)*16 + quad*4;   // voxel = d*8 + p
      const int d = vox0 >> 3;
      f32x4 v;
#pragma unroll
      for (int r = 0; r < 4; ++r)
        v[r] = acc[mt][r] + bb +
               (float)*(const _Float16*)(XtB + xsw(vox0 + r, o));
      *(f32x4*)(outp + (size_t)d*4096 + (vox0 & 7)) = v;
    }
  }
}

extern "C" void kernel_launch(void* const* d_in, const int* in_sizes, int n_in,
                              void* d_out, int out_size, void* d_ws, size_t ws_size,
                              hipStream_t stream) {
  const float* x  = (const float*)d_in[0];
  const float* Wk = (const float*)d_in[1];
  const float* bk = (const float*)d_in[2];
  const float* Wq = (const float*)d_in[3];
  const float* bq = (const float*)d_in[4];
  const float* Wv = (const float*)d_in[5];
  const float* bv = (const float*)d_in[6];
  const float* Wo = (const float*)d_in[7];
  const float* bo = (const float*)d_in[8];
  float* out = (float*)d_out;
  _Float16* wh = (_Float16*)d_ws;
  float* bf = (float*)((char*)d_ws + 65536);
  _Float16* Xg = (_Float16*)((char*)d_ws + 131072);  // needs 67.1 MB of ws

  prep_kernel<<<dim3(128), dim3(128), 0, stream>>>(Wk, bk, Wq, bq, Wv, bv, Wo, bo, wh, bf);
  transpose_kernel<<<dim3(4096), dim3(256), 0, stream>>>(x, Xg);
  attn_kernel<<<dim3(1024), dim3(1024), 0, stream>>>(Xg, wh, bf, out);
}